// Round 6
// baseline (244.839 us; speedup 1.0000x reference)
//
#include <hip/hip_runtime.h>
#include <stddef.h>

constexpr int FEAT = 256;
constexpr int F4   = FEAT / 4;       // 64 float4 per row
constexpr int NCLS = 345;
constexpr int NDOM = 6;
constexpr int NSEG = NCLS * NDOM;    // 2070
constexpr int SB   = 256;            // scatter blocks (== k_bases block size)
constexpr int QS   = 4;              // quarters per segment in the reduce
constexpr float BETA = 0.5f;
constexpr float EPS  = 1e-5f;

typedef float f32x4 __attribute__((ext_vector_type(4)));

// ---- phase A: seg[] + per-block histogram (no global atomics) ----
__global__ void __launch_bounds__(256)
k_seg_hist(const int* __restrict__ labels, const int* __restrict__ domains,
           int n, int chunk, int* __restrict__ seg, int* __restrict__ W) {
    __shared__ int h[NSEG];
    for (int i = threadIdx.x; i < NSEG; i += blockDim.x) h[i] = 0;
    __syncthreads();
    const int b  = blockIdx.x;
    const int lo = b * chunk;
    const int hi = min(n, lo + chunk);
    for (int i = lo + threadIdx.x; i < hi; i += blockDim.x) {
        int s = domains[i] * NCLS + labels[i];
        seg[i] = s;
        atomicAdd(&h[s], 1);
    }
    __syncthreads();
    int* Wb = W + (size_t)b * NSEG;
    for (int i = threadIdx.x; i < NSEG; i += blockDim.x) Wb[i] = h[i];
}

// ---- phase B (fused): per-block LOCAL prefix -> Bmat, column total -> totals ----
__global__ void __launch_bounds__(256)
k_bases_tot(const int* __restrict__ W, int* __restrict__ Bmat,
            int* __restrict__ totals) {
    const int s = blockIdx.x;
    const int t = threadIdx.x;  // 256 == SB
    __shared__ int sc[SB];
    int w = W[(size_t)t * NSEG + s];
    sc[t] = w;
    __syncthreads();
    for (int off = 1; off < SB; off <<= 1) {
        int v = (t >= off) ? sc[t - off] : 0;
        __syncthreads();
        sc[t] += v;
        __syncthreads();
    }
    Bmat[(size_t)t * NSEG + s] = sc[t] - w;   // local exclusive prefix
    if (t == SB - 1) totals[s] = sc[t];
}

// ---- phase C: scatter; offsets-scan fused in LDS (block 0 persists offsets) ----
__global__ void __launch_bounds__(256)
k_scatter(const int* __restrict__ seg, int n, int chunk,
          const int* __restrict__ Bmat, const int* __restrict__ totals,
          int* __restrict__ offsets, int* __restrict__ sorted) {
    constexpr int CH = (NSEG + 255) / 256;  // 9
    __shared__ int cur[NSEG];
    __shared__ int toff[NSEG];
    __shared__ int csum[256];
    const int b = blockIdx.x;
    const int t = threadIdx.x;

    // load totals, in-LDS exclusive scan (each thread owns chunk [t*CH, t*CH+CH))
    for (int i = t; i < NSEG; i += 256) toff[i] = totals[i];
    __syncthreads();
    const int cbase = t * CH;
    int sum = 0;
    for (int j = 0; j < CH; ++j) {
        int idx = cbase + j;
        if (idx < NSEG) sum += toff[idx];
    }
    csum[t] = sum;
    __syncthreads();
    for (int off = 1; off < 256; off <<= 1) {
        int v = (t >= off) ? csum[t - off] : 0;
        __syncthreads();
        csum[t] += v;
        __syncthreads();
    }
    int run = csum[t] - sum;
    for (int j = 0; j < CH; ++j) {
        int idx = cbase + j;
        if (idx < NSEG) { int v = toff[idx]; toff[idx] = run; run += v; }
    }
    __syncthreads();

    const int* Bb = Bmat + (size_t)b * NSEG;
    for (int i = t; i < NSEG; i += 256) {
        cur[i] = Bb[i] + toff[i];
        if (b == 0) offsets[i] = toff[i];
    }
    __syncthreads();

    const int lo = b * chunk;
    const int hi = min(n, lo + chunk);
    for (int i = lo + t; i < hi; i += 256) {
        int s = seg[i];
        int pos = atomicAdd(&cur[s], 1);
        sorted[pos] = i;
    }
}

// ---- phase D: quarter-segment reduce -> deterministic partials ----
__global__ void __launch_bounds__(256)
k_reduce4(const float* __restrict__ feats, const int* __restrict__ sorted,
          const int* __restrict__ totals, const int* __restrict__ offsets,
          float* __restrict__ partial) {
    const int b   = blockIdx.x;
    const int seg = b >> 2;
    const int q   = b & 3;
    const int cnt = totals[seg];
    const int cq  = (cnt + QS - 1) >> 2;
    const int lo  = min(cnt, q * cq);
    const int hi  = min(cnt, lo + cq);
    const int qn  = hi - lo;
    const int qbase = offsets[seg] + lo;

    const int lane = threadIdx.x & 63;   // f4 column within the 1 KB row
    const int rp   = threadIdx.x >> 6;   // wave 0..3

    f32x4 acc = (f32x4)0.0f;
    int r = rp;
    for (; r + 28 < qn; r += 32) {
        int i0 = sorted[qbase + r];
        int i1 = sorted[qbase + r + 4];
        int i2 = sorted[qbase + r + 8];
        int i3 = sorted[qbase + r + 12];
        int i4 = sorted[qbase + r + 16];
        int i5 = sorted[qbase + r + 20];
        int i6 = sorted[qbase + r + 24];
        int i7 = sorted[qbase + r + 28];
        f32x4 v0 = reinterpret_cast<const f32x4*>(feats + (size_t)i0 * FEAT)[lane];
        f32x4 v1 = reinterpret_cast<const f32x4*>(feats + (size_t)i1 * FEAT)[lane];
        f32x4 v2 = reinterpret_cast<const f32x4*>(feats + (size_t)i2 * FEAT)[lane];
        f32x4 v3 = reinterpret_cast<const f32x4*>(feats + (size_t)i3 * FEAT)[lane];
        f32x4 v4 = reinterpret_cast<const f32x4*>(feats + (size_t)i4 * FEAT)[lane];
        f32x4 v5 = reinterpret_cast<const f32x4*>(feats + (size_t)i5 * FEAT)[lane];
        f32x4 v6 = reinterpret_cast<const f32x4*>(feats + (size_t)i6 * FEAT)[lane];
        f32x4 v7 = reinterpret_cast<const f32x4*>(feats + (size_t)i7 * FEAT)[lane];
        acc += (v0 + v1) + (v2 + v3) + ((v4 + v5) + (v6 + v7));
    }
    for (; r < qn; r += 4) {
        int i0 = sorted[qbase + r];
        acc += reinterpret_cast<const f32x4*>(feats + (size_t)i0 * FEAT)[lane];
    }

    __shared__ f32x4 sh[4][F4];
    sh[rp][lane] = acc;
    __syncthreads();
    if (rp == 0) {
        f32x4 s = acc + sh[1][lane] + sh[2][lane] + sh[3][lane];
        reinterpret_cast<f32x4*>(partial)[(size_t)b * F4 + lane] = s;
    }
}

// ---- phase E: sum partials, normalize, mask, blend ----
__global__ void k_final(const float* __restrict__ partial, const float* __restrict__ mean,
                        const float* __restrict__ amount, const int* __restrict__ totals,
                        float* __restrict__ out) {
    const int seg  = blockIdx.x;
    const int lane = threadIdx.x;  // 64 threads
    const int cnt  = totals[seg];
    const f32x4* P = reinterpret_cast<const f32x4*>(partial);
    f32x4 s = P[(size_t)(4 * seg + 0) * F4 + lane]
            + P[(size_t)(4 * seg + 1) * F4 + lane]
            + P[(size_t)(4 * seg + 2) * F4 + lane]
            + P[(size_t)(4 * seg + 3) * F4 + lane];
    float inv = 1.0f / ((float)cnt + EPS);
    f32x4 tm = s * inv;

    float lsum = tm.x + tm.y + tm.z + tm.w;
    for (int off = 1; off < 64; off <<= 1) lsum += __shfl_xor(lsum, off, 64);
    bool msk = (lsum != 0.0f);

    f32x4 m4 = reinterpret_cast<const f32x4*>(mean)[(size_t)seg * F4 + lane];
    f32x4 o = msk ? (m4 * BETA + tm * (1.0f - BETA)) : m4;
    reinterpret_cast<f32x4*>(out)[(size_t)seg * F4 + lane] = o;
    if (lane == 0) {
        out[(size_t)NSEG * FEAT + seg] = (cnt > 0) ? 1.0f : amount[seg];
    }
}

// ---------------- fallback (workspace too small): atomic accumulate into d_out ----------------
__global__ void k_fb_zero(float* __restrict__ out, int total) {
    int stride = gridDim.x * blockDim.x;
    for (int i = blockIdx.x * blockDim.x + threadIdx.x; i < total; i += stride) out[i] = 0.f;
}

__global__ void k_fb_acc(const float* __restrict__ feats, const int* __restrict__ labels,
                         const int* __restrict__ domains, int n, float* __restrict__ out) {
    int lane   = threadIdx.x & 63;
    int gwave  = (blockIdx.x * blockDim.x + threadIdx.x) >> 6;
    int nwaves = (gridDim.x * blockDim.x) >> 6;
    for (int i = gwave; i < n; i += nwaves) {
        int seg = domains[i] * NCLS + labels[i];
        const float4 v = reinterpret_cast<const float4*>(feats + (size_t)i * FEAT)[lane];
        float* dst = out + (size_t)seg * FEAT + lane * 4;
        atomicAdd(dst + 0, v.x);
        atomicAdd(dst + 1, v.y);
        atomicAdd(dst + 2, v.z);
        atomicAdd(dst + 3, v.w);
        if (lane == 0) atomicAdd(out + (size_t)NSEG * FEAT + seg, 1.0f);
    }
}

__global__ void k_fb_epi(const float* __restrict__ mean, const float* __restrict__ amount,
                         float* __restrict__ out) {
    int seg  = blockIdx.x;
    int lane = threadIdx.x;  // 64 threads
    float cntf = out[(size_t)NSEG * FEAT + seg];
    float4 s = reinterpret_cast<float4*>(out)[(size_t)seg * F4 + lane];
    float inv = 1.0f / (cntf + EPS);
    float4 tm = make_float4(s.x * inv, s.y * inv, s.z * inv, s.w * inv);
    float lsum = tm.x + tm.y + tm.z + tm.w;
    for (int off = 1; off < 64; off <<= 1) lsum += __shfl_xor(lsum, off, 64);
    bool msk = (lsum != 0.0f);
    float4 m4 = reinterpret_cast<const float4*>(mean)[(size_t)seg * F4 + lane];
    float4 o;
    if (msk) {
        o.x = m4.x * BETA + tm.x * (1.f - BETA);
        o.y = m4.y * BETA + tm.y * (1.f - BETA);
        o.z = m4.z * BETA + tm.z * (1.f - BETA);
        o.w = m4.w * BETA + tm.w * (1.f - BETA);
    } else {
        o = m4;
    }
    reinterpret_cast<float4*>(out)[(size_t)seg * F4 + lane] = o;
    if (lane == 0) {
        out[(size_t)NSEG * FEAT + seg] = (cntf > 0.5f) ? 1.0f : amount[seg];
    }
}

extern "C" void kernel_launch(void* const* d_in, const int* in_sizes, int n_in,
                              void* d_out, int out_size, void* d_ws, size_t ws_size,
                              hipStream_t stream) {
    const float* feats   = (const float*)d_in[0];
    const float* mean    = (const float*)d_in[1];
    const float* amount  = (const float*)d_in[2];
    const int*   labels  = (const int*)d_in[3];
    const int*   domains = (const int*)d_in[4];
    float* out = (float*)d_out;
    const int n = in_sizes[3];  // number of rows
    const int chunk = (n + SB - 1) / SB;

    // ws layout (16B-aligned blocks first):
    //   seg[n] | sorted[n] | W[SB*NSEG] | Bmat[SB*NSEG] | partial[QS*NSEG*FEAT f32]
    //   | totals[NSEG] | offsets[NSEG]
    size_t need = ((size_t)n * 2 + (size_t)SB * NSEG * 2
                   + (size_t)QS * NSEG * FEAT + (size_t)NSEG * 2) * sizeof(int);
    if (ws_size >= need) {
        int*   seg     = (int*)d_ws;
        int*   sorted  = seg + n;
        int*   W       = sorted + n;
        int*   Bmat    = W + (size_t)SB * NSEG;
        float* partial = (float*)(Bmat + (size_t)SB * NSEG);
        int*   totals  = (int*)(partial + (size_t)QS * NSEG * FEAT);
        int*   offsets = totals + NSEG;

        k_seg_hist<<<SB, 256, 0, stream>>>(labels, domains, n, chunk, seg, W);
        k_bases_tot<<<NSEG, 256, 0, stream>>>(W, Bmat, totals);
        k_scatter<<<SB, 256, 0, stream>>>(seg, n, chunk, Bmat, totals, offsets, sorted);
        k_reduce4<<<QS * NSEG, 256, 0, stream>>>(feats, sorted, totals, offsets, partial);
        k_final<<<NSEG, 64, 0, stream>>>(partial, mean, amount, totals, out);
    } else {
        int total = NSEG * FEAT + NSEG;
        k_fb_zero<<<(total + 255) / 256, 256, 0, stream>>>(out, total);
        k_fb_acc<<<2048, 256, 0, stream>>>(feats, labels, domains, n, out);
        k_fb_epi<<<NSEG, 64, 0, stream>>>(mean, amount, out);
    }
}

// Round 7
// 235.611 us; speedup vs baseline: 1.0392x; 1.0392x over previous
//
#include <hip/hip_runtime.h>
#include <stddef.h>

constexpr int FEAT = 256;
constexpr int F4   = FEAT / 4;       // 64 float4 per row
constexpr int NCLS = 345;
constexpr int NDOM = 6;
constexpr int NSEG = NCLS * NDOM;    // 2070
constexpr int SB   = 256;            // scatter blocks (== k_bases block size)
constexpr int NTAIL = 22;            // segments beyond the 2048 co-resident slots
constexpr int NFULL = NSEG - NTAIL;  // 2048: one fused-epilogue block each
constexpr float BETA = 0.5f;
constexpr float EPS  = 1e-5f;

typedef float f32x4 __attribute__((ext_vector_type(4)));

// ---- phase A: per-block histogram (no global atomics, no seg[] write) ----
__global__ void __launch_bounds__(256)
k_hist(const int* __restrict__ labels, const int* __restrict__ domains,
       int n, int chunk, int* __restrict__ W) {
    __shared__ int h[NSEG];
    for (int i = threadIdx.x; i < NSEG; i += blockDim.x) h[i] = 0;
    __syncthreads();
    const int b  = blockIdx.x;
    const int lo = b * chunk;
    const int hi = min(n, lo + chunk);
    for (int i = lo + threadIdx.x; i < hi; i += blockDim.x) {
        int s = domains[i] * NCLS + labels[i];
        atomicAdd(&h[s], 1);
    }
    __syncthreads();
    int* Wb = W + (size_t)b * NSEG;
    for (int i = threadIdx.x; i < NSEG; i += blockDim.x) Wb[i] = h[i];
}

// ---- phase B: per-block LOCAL prefix -> Bmat, column total -> totals ----
__global__ void __launch_bounds__(256)
k_bases_tot(const int* __restrict__ W, int* __restrict__ Bmat,
            int* __restrict__ totals) {
    const int s = blockIdx.x;
    const int t = threadIdx.x;  // 256 == SB
    __shared__ int sc[SB];
    int w = W[(size_t)t * NSEG + s];
    sc[t] = w;
    __syncthreads();
    for (int off = 1; off < SB; off <<= 1) {
        int v = (t >= off) ? sc[t - off] : 0;
        __syncthreads();
        sc[t] += v;
        __syncthreads();
    }
    Bmat[(size_t)t * NSEG + s] = sc[t] - w;   // local exclusive prefix
    if (t == SB - 1) totals[s] = sc[t];
}

// ---- phase C: exclusive scan of totals -> offsets (single block) ----
__global__ void k_scan(const int* __restrict__ totals, int* __restrict__ offsets) {
    constexpr int T  = 256;
    constexpr int CH = (NSEG + T - 1) / T;  // 9
    __shared__ int csum[T];
    int t = threadIdx.x;
    int base = t * CH;
    int sum = 0;
    for (int j = 0; j < CH; ++j) {
        int idx = base + j;
        if (idx < NSEG) sum += totals[idx];
    }
    csum[t] = sum;
    __syncthreads();
    for (int off = 1; off < T; off <<= 1) {
        int v = (t >= off) ? csum[t - off] : 0;
        __syncthreads();
        csum[t] += v;
        __syncthreads();
    }
    int run = csum[t] - sum;
    for (int j = 0; j < CH; ++j) {
        int idx = base + j;
        if (idx < NSEG) {
            offsets[idx] = run;
            run += totals[idx];
        }
    }
}

// ---- phase D: scatter row indices (seg recomputed; LDS cursors) ----
__global__ void __launch_bounds__(256)
k_scatter(const int* __restrict__ labels, const int* __restrict__ domains,
          int n, int chunk, const int* __restrict__ Bmat,
          const int* __restrict__ offsets, int* __restrict__ sorted) {
    __shared__ int cur[NSEG];
    const int b = blockIdx.x;
    const int* Bb = Bmat + (size_t)b * NSEG;
    for (int i = threadIdx.x; i < NSEG; i += blockDim.x) cur[i] = Bb[i] + offsets[i];
    __syncthreads();
    const int lo = b * chunk;
    const int hi = min(n, lo + chunk);
    for (int i = lo + threadIdx.x; i < hi; i += blockDim.x) {
        int s = domains[i] * NCLS + labels[i];
        int pos = atomicAdd(&cur[s], 1);
        sorted[pos] = i;
    }
}

// ---- phase E: reduce. Blocks 0..NFULL-1: whole segment + fused epilogue.
//      Blocks NFULL..NFULL+4*NTAIL-1: quarter of a tail segment -> partial. ----
__global__ void __launch_bounds__(256)
k_reduce_mixed(const float* __restrict__ feats, const float* __restrict__ mean,
               const float* __restrict__ amount, const int* __restrict__ sorted,
               const int* __restrict__ totals, const int* __restrict__ offsets,
               float* __restrict__ partial, float* __restrict__ out) {
    const int b = blockIdx.x;
    int seg, lo, hi, pslot = 0;
    if (b < NFULL) {
        seg = b;
        lo = 0;
        hi = totals[seg];
    } else {
        const int j  = b - NFULL;           // 0..4*NTAIL-1
        seg = NFULL + (j >> 2);
        const int q  = j & 3;
        const int cnt = totals[seg];
        const int cq  = (cnt + 3) >> 2;
        lo = min(cnt, q * cq);
        hi = min(cnt, lo + cq);
        pslot = j;
    }
    const int qn   = hi - lo;
    const int base = offsets[seg] + lo;
    const int lane = threadIdx.x & 63;   // f4 column within the 1 KB row
    const int rp   = threadIdx.x >> 6;   // wave 0..3

    f32x4 acc = (f32x4)0.0f;
    int r = rp;
    for (; r + 28 < qn; r += 32) {
        int i0 = sorted[base + r];
        int i1 = sorted[base + r + 4];
        int i2 = sorted[base + r + 8];
        int i3 = sorted[base + r + 12];
        int i4 = sorted[base + r + 16];
        int i5 = sorted[base + r + 20];
        int i6 = sorted[base + r + 24];
        int i7 = sorted[base + r + 28];
        f32x4 v0 = reinterpret_cast<const f32x4*>(feats + (size_t)i0 * FEAT)[lane];
        f32x4 v1 = reinterpret_cast<const f32x4*>(feats + (size_t)i1 * FEAT)[lane];
        f32x4 v2 = reinterpret_cast<const f32x4*>(feats + (size_t)i2 * FEAT)[lane];
        f32x4 v3 = reinterpret_cast<const f32x4*>(feats + (size_t)i3 * FEAT)[lane];
        f32x4 v4 = reinterpret_cast<const f32x4*>(feats + (size_t)i4 * FEAT)[lane];
        f32x4 v5 = reinterpret_cast<const f32x4*>(feats + (size_t)i5 * FEAT)[lane];
        f32x4 v6 = reinterpret_cast<const f32x4*>(feats + (size_t)i6 * FEAT)[lane];
        f32x4 v7 = reinterpret_cast<const f32x4*>(feats + (size_t)i7 * FEAT)[lane];
        acc += (v0 + v1) + (v2 + v3) + ((v4 + v5) + (v6 + v7));
    }
    for (; r < qn; r += 4) {
        int i0 = sorted[base + r];
        acc += reinterpret_cast<const f32x4*>(feats + (size_t)i0 * FEAT)[lane];
    }

    __shared__ f32x4 sh[4][F4];
    sh[rp][lane] = acc;
    __syncthreads();
    if (rp == 0) {
        f32x4 s = acc + sh[1][lane] + sh[2][lane] + sh[3][lane];
        if (b < NFULL) {
            const int cnt = hi;  // lo == 0
            float inv = 1.0f / ((float)cnt + EPS);
            f32x4 tm = s * inv;
            float lsum = tm.x + tm.y + tm.z + tm.w;
            for (int off = 1; off < 64; off <<= 1) lsum += __shfl_xor(lsum, off, 64);
            bool msk = (lsum != 0.0f);
            f32x4 m4 = reinterpret_cast<const f32x4*>(mean)[(size_t)seg * F4 + lane];
            f32x4 o = msk ? (m4 * BETA + tm * (1.0f - BETA)) : m4;
            reinterpret_cast<f32x4*>(out)[(size_t)seg * F4 + lane] = o;
            if (lane == 0) {
                out[(size_t)NSEG * FEAT + seg] = (cnt > 0) ? 1.0f : amount[seg];
            }
        } else {
            reinterpret_cast<f32x4*>(partial)[(size_t)pslot * F4 + lane] = s;
        }
    }
}

// ---- phase F: combine tail partials + epilogue (22 blocks) ----
__global__ void k_final_tail(const float* __restrict__ partial, const float* __restrict__ mean,
                             const float* __restrict__ amount, const int* __restrict__ totals,
                             float* __restrict__ out) {
    const int ts   = blockIdx.x;          // 0..NTAIL-1
    const int seg  = NFULL + ts;
    const int lane = threadIdx.x;         // 64 threads
    const int cnt  = totals[seg];
    const f32x4* P = reinterpret_cast<const f32x4*>(partial);
    f32x4 s = P[(size_t)(4 * ts + 0) * F4 + lane]
            + P[(size_t)(4 * ts + 1) * F4 + lane]
            + P[(size_t)(4 * ts + 2) * F4 + lane]
            + P[(size_t)(4 * ts + 3) * F4 + lane];
    float inv = 1.0f / ((float)cnt + EPS);
    f32x4 tm = s * inv;

    float lsum = tm.x + tm.y + tm.z + tm.w;
    for (int off = 1; off < 64; off <<= 1) lsum += __shfl_xor(lsum, off, 64);
    bool msk = (lsum != 0.0f);

    f32x4 m4 = reinterpret_cast<const f32x4*>(mean)[(size_t)seg * F4 + lane];
    f32x4 o = msk ? (m4 * BETA + tm * (1.0f - BETA)) : m4;
    reinterpret_cast<f32x4*>(out)[(size_t)seg * F4 + lane] = o;
    if (lane == 0) {
        out[(size_t)NSEG * FEAT + seg] = (cnt > 0) ? 1.0f : amount[seg];
    }
}

// ---------------- fallback (workspace too small): atomic accumulate into d_out ----------------
__global__ void k_fb_zero(float* __restrict__ out, int total) {
    int stride = gridDim.x * blockDim.x;
    for (int i = blockIdx.x * blockDim.x + threadIdx.x; i < total; i += stride) out[i] = 0.f;
}

__global__ void k_fb_acc(const float* __restrict__ feats, const int* __restrict__ labels,
                         const int* __restrict__ domains, int n, float* __restrict__ out) {
    int lane   = threadIdx.x & 63;
    int gwave  = (blockIdx.x * blockDim.x + threadIdx.x) >> 6;
    int nwaves = (gridDim.x * blockDim.x) >> 6;
    for (int i = gwave; i < n; i += nwaves) {
        int seg = domains[i] * NCLS + labels[i];
        const float4 v = reinterpret_cast<const float4*>(feats + (size_t)i * FEAT)[lane];
        float* dst = out + (size_t)seg * FEAT + lane * 4;
        atomicAdd(dst + 0, v.x);
        atomicAdd(dst + 1, v.y);
        atomicAdd(dst + 2, v.z);
        atomicAdd(dst + 3, v.w);
        if (lane == 0) atomicAdd(out + (size_t)NSEG * FEAT + seg, 1.0f);
    }
}

__global__ void k_fb_epi(const float* __restrict__ mean, const float* __restrict__ amount,
                         float* __restrict__ out) {
    int seg  = blockIdx.x;
    int lane = threadIdx.x;  // 64 threads
    float cntf = out[(size_t)NSEG * FEAT + seg];
    float4 s = reinterpret_cast<float4*>(out)[(size_t)seg * F4 + lane];
    float inv = 1.0f / (cntf + EPS);
    float4 tm = make_float4(s.x * inv, s.y * inv, s.z * inv, s.w * inv);
    float lsum = tm.x + tm.y + tm.z + tm.w;
    for (int off = 1; off < 64; off <<= 1) lsum += __shfl_xor(lsum, off, 64);
    bool msk = (lsum != 0.0f);
    float4 m4 = reinterpret_cast<const float4*>(mean)[(size_t)seg * F4 + lane];
    float4 o;
    if (msk) {
        o.x = m4.x * BETA + tm.x * (1.f - BETA);
        o.y = m4.y * BETA + tm.y * (1.f - BETA);
        o.z = m4.z * BETA + tm.z * (1.f - BETA);
        o.w = m4.w * BETA + tm.w * (1.f - BETA);
    } else {
        o = m4;
    }
    reinterpret_cast<float4*>(out)[(size_t)seg * F4 + lane] = o;
    if (lane == 0) {
        out[(size_t)NSEG * FEAT + seg] = (cntf > 0.5f) ? 1.0f : amount[seg];
    }
}

extern "C" void kernel_launch(void* const* d_in, const int* in_sizes, int n_in,
                              void* d_out, int out_size, void* d_ws, size_t ws_size,
                              hipStream_t stream) {
    const float* feats   = (const float*)d_in[0];
    const float* mean    = (const float*)d_in[1];
    const float* amount  = (const float*)d_in[2];
    const int*   labels  = (const int*)d_in[3];
    const int*   domains = (const int*)d_in[4];
    float* out = (float*)d_out;
    const int n = in_sizes[3];  // number of rows
    const int chunk = (n + SB - 1) / SB;

    // ws layout: sorted[n] | W[SB*NSEG] | Bmat[SB*NSEG]
    //            | partial[4*NTAIL*FEAT f32] | totals[NSEG] | offsets[NSEG]
    size_t need = ((size_t)n + (size_t)SB * NSEG * 2
                   + (size_t)4 * NTAIL * FEAT + (size_t)NSEG * 2) * sizeof(int);
    if (ws_size >= need) {
        int*   sorted  = (int*)d_ws;
        int*   W       = sorted + n;
        int*   Bmat    = W + (size_t)SB * NSEG;
        float* partial = (float*)(Bmat + (size_t)SB * NSEG);
        int*   totals  = (int*)(partial + (size_t)4 * NTAIL * FEAT);
        int*   offsets = totals + NSEG;

        k_hist<<<SB, 256, 0, stream>>>(labels, domains, n, chunk, W);
        k_bases_tot<<<NSEG, 256, 0, stream>>>(W, Bmat, totals);
        k_scan<<<1, 256, 0, stream>>>(totals, offsets);
        k_scatter<<<SB, 256, 0, stream>>>(labels, domains, n, chunk, Bmat, offsets, sorted);
        k_reduce_mixed<<<NFULL + 4 * NTAIL, 256, 0, stream>>>(
            feats, mean, amount, sorted, totals, offsets, partial, out);
        k_final_tail<<<NTAIL, 64, 0, stream>>>(partial, mean, amount, totals, out);
    } else {
        int total = NSEG * FEAT + NSEG;
        k_fb_zero<<<(total + 255) / 256, 256, 0, stream>>>(out, total);
        k_fb_acc<<<2048, 256, 0, stream>>>(feats, labels, domains, n, out);
        k_fb_epi<<<NSEG, 64, 0, stream>>>(mean, amount, out);
    }
}